// Round 9
// baseline (537.734 us; speedup 1.0000x reference)
//
#include <hip/hip_runtime.h>

// Problem constants (from reference)
#define NCH   52            // NC
#define NSs   128           // NS (scan length)
#define NRAYS 64
#define INNER 64            // NR*NT = 4*16; one wave covers one (ray, ch) slab
#define XS    (3*NCH*INNER) // per-s stride in x       = 9984 floats
#define ZS    (2*NCH*INNER) // per-s stride in z_vals  = 6656 floats
#define NOUT  (NRAYS*NCH*INNER)  // 212992 complex outputs
#define NBLK  (NRAYS*NCH)   // 3328 blocks = exactly 13 per CU on 256 CUs

// Recurrence (reference semantics, verified in prior rounds):
//   f[t]   = (1-alpha[t]) * e^{-i*w*(z[t+1]-z[t])} + 1e-10   (real-part add)
//   P[s]   = prod_{t<s} f[t],  P[0] = 0  (exclusive cumprod, slot0 forced 0)
//   out    = sum_s ch[s] * (ampc/z[s]) * alpha[s] * P[s]
//
// THIS VERSION: 4-way segmented prefix-product. The 128-step serial chain is
// split into 4 segments of 32 steps; block = 256 threads = 4 waves, wave k
// handles segment k (s in [32k, 32k+32)) of all 64 chains of one (ray,ch)
// slab. Each thread produces (sum_k, F_k) where sum_k is the local
// contribution sum with segment-local exclusive products Q_k, and F_k is the
// full product of its segment's factors. LDS combine:
//   out = sum0 + F0*(sum1 + F1*(sum2 + F2*sum3))
// This is pure reassociation of the same f32 products.
//
// Why: previous kernel ran 832 blocks = 3.25/CU (13 waves/CU, unbalanced
// 4-vs-3 blocks per CU) and achieved only ~3.2 TB/s of a 6.5 TB/s ceiling.
// 3328 blocks = perfect 13/CU balance, 32 resident waves/CU (HW max) ->
// 2.5x in-flight memory streams. Traffic unchanged (+3 duplicated z-rows).
//
// Output layout: PLANAR float32 — [all 212992 reals][all 212992 imags]
__global__ __launch_bounds__(256) void render_kernel(
    const float* __restrict__ x,
    const float* __restrict__ zv,
    const float* __restrict__ fc,
    float* __restrict__ out)
{
    const int rc    = blockIdx.x;            // slab id: 0..3327
    const int inner = threadIdx.x & (INNER - 1);
    const int seg   = threadIdx.x >> 6;      // 0..3, wave-uniform
    const int c     = rc % NCH;
    const int r     = rc / NCH;

    const float* xp = x  + (size_t)r * NSs * XS + c * INNER + inner;
    const float* zp = zv + (size_t)r * NSs * ZS + c * INNER + inner;

    const double C_L    = 299792458.0;
    const double PI_D   = 3.14159265358979323846;
    const float  fcd    = fc[NCH + c];
    // revolutions per unit distance: (2*pi*fc*1e9/C)/(2*pi) = fc*1e9/C
    const double fc_rev = (double)fcd * 1.0e9 / C_L;
    const float  ampc   = (float)(C_L / ((double)fcd * 1.0e9 * 4.0 * PI_D));

    const int s0 = seg * 32;
    float z_cur = zp[(size_t)s0 * ZS];
    float Pre, Pim;                // segment-local running product Q
    float accre = 0.0f, accim = 0.0f;
    int s = s0;

    if (seg == 0) {
        // s = 0: P[0] = 0 -> no contribution; build f[0] into Q.
        float z1  = zp[ZS];
        float ar0 = xp[(size_t)2 * NCH * INNER];
        float oma0 = __expf(-ar0);           // (1 - alpha[0])
        double u0 = fc_rev * (double)(z1 - z_cur);
        u0 -= floor(u0);                     // fractional revolutions [0,1)
        float uf0 = (float)u0;
        float sn0 = __builtin_amdgcn_sinf(uf0);   // sin(2*pi*u)
        float cs0 = __builtin_amdgcn_cosf(uf0);   // cos(2*pi*u)
        Pre = fmaf(oma0, cs0, 1e-10f);       // f = (1-alpha)*e^{-i th} + 1e-10
        Pim = -oma0 * sn0;                   // (+1e-10 on real part only)
        z_cur = z1;
        s = 1;
    } else {
        Pre = 1.0f;                          // Q[s0] = 1 (exclusive local prod)
        Pim = 0.0f;
    }

    const int send = s0 + 32;                // exclusive end

#pragma unroll 4
    for (; s < send; ++s) {
        float xre = xp[(size_t)s * XS];
        float xim = xp[(size_t)s * XS + NCH * INNER];
        float ar  = xp[(size_t)s * XS + 2 * NCH * INNER];
        // z[s+1]; for s=127 clamp to z[127] (f[127] is never consumed:
        // it only enters F3, which the combine ignores).
        int   sn_i = (s + 1 < NSs) ? (s + 1) : (NSs - 1);
        float zn   = zp[(size_t)sn_i * ZS];

        // contribution for s: ch * amp_decay * (alpha * Q)
        float oma   = __expf(-ar);           // (1 - alpha)
        float alpha = 1.0f - oma;
        float amp   = ampc * __builtin_amdgcn_rcpf(z_cur);
        float k     = alpha * amp;
        float cre   = k * Pre;
        float cim   = k * Pim;
        accre = fmaf(xre, cre, fmaf(-xim, cim, accre));
        accim = fmaf(xre, cim, fmaf( xim, cre, accim));

        // fold f[s] into Q
        double u = fc_rev * (double)(zn - z_cur);
        u -= floor(u);                       // fractional revolutions [0,1)
        float uf = (float)u;
        float sn = __builtin_amdgcn_sinf(uf);
        float cs = __builtin_amdgcn_cosf(uf);
        float fre = fmaf(oma, cs, 1e-10f);
        float fim = -oma * sn;
        float nre = Pre * fre - Pim * fim;
        float nim = fmaf(Pre, fim, Pim * fre);
        Pre = nre;
        Pim = nim;
        z_cur = zn;
    }

    // ---- combine the 4 segments in LDS ----
    // comb[k][inner] = (sum_re, sum_im, F_re, F_im) for segment k
    __shared__ float4 comb[4][INNER];
    comb[seg][inner] = make_float4(accre, accim, Pre, Pim);
    __syncthreads();

    if (seg == 0) {
        float4 c3 = comb[3][inner];
        float4 c2 = comb[2][inner];
        float4 c1 = comb[1][inner];
        // o = sum3
        float ore = c3.x, oim = c3.y, t;
        // o = sum2 + F2*o
        t   = c2.x + c2.z * ore - c2.w * oim;
        oim = c2.y + c2.z * oim + c2.w * ore;
        ore = t;
        // o = sum1 + F1*o
        t   = c1.x + c1.z * ore - c1.w * oim;
        oim = c1.y + c1.z * oim + c1.w * ore;
        ore = t;
        // o = sum0 + F0*o   (sum0, F0 still live in this thread's registers)
        t   = accre + Pre * ore - Pim * oim;
        oim = accim + Pre * oim + Pim * ore;
        ore = t;

        const int oidx = rc * INNER + inner;
        out[oidx]        = ore;   // real plane
        out[NOUT + oidx] = oim;   // imag plane
    }
}

extern "C" void kernel_launch(void* const* d_in, const int* in_sizes, int n_in,
                              void* d_out, int out_size, void* d_ws, size_t ws_size,
                              hipStream_t stream) {
    const float* x  = (const float*)d_in[0];
    const float* zv = (const float*)d_in[1];
    const float* fc = (const float*)d_in[2];
    float* out = (float*)d_out;

    render_kernel<<<NBLK, 256, 0, stream>>>(x, zv, fc, out);
}